// Round 1
// baseline (323.099 us; speedup 1.0000x reference)
//
#include <hip/hip_runtime.h>

// Heat2D: B=C=H=W=KD=64.
// Pipeline:
//   k0: cos table C[i][j] = cos(i*j*pi/64)/64  (symmetric)
//   k1: z = LN(freq)@Wz+bz; siluzT[c][h][w], wexpT[c][n][m] (transposed layouts)
//   k2: per (b,h): LN_c(x[b,:,h,:]^T + freq[h]) @ Wk + bk -> planes[b][n][h][w]
//   k3: per (b,c): P2 = C*((C*P*C) .* wexp_c)*C, in-place on planes (C symmetric)
//   k4: per (b,h): (LN_c(planes)*g_o+b_o)*siluz @ Wo + bo -> out[b][co][h][w]
// All fp32. LDS strides padded to 68 dwords (16B-aligned rows, bank-floor access).

#define PADR 68

__device__ __forceinline__ void fma16(float (&acc)[4][4], float4 a, float4 b) {
    acc[0][0] = fmaf(a.x, b.x, acc[0][0]);
    acc[0][1] = fmaf(a.x, b.y, acc[0][1]);
    acc[0][2] = fmaf(a.x, b.z, acc[0][2]);
    acc[0][3] = fmaf(a.x, b.w, acc[0][3]);
    acc[1][0] = fmaf(a.y, b.x, acc[1][0]);
    acc[1][1] = fmaf(a.y, b.y, acc[1][1]);
    acc[1][2] = fmaf(a.y, b.z, acc[1][2]);
    acc[1][3] = fmaf(a.y, b.w, acc[1][3]);
    acc[2][0] = fmaf(a.z, b.x, acc[2][0]);
    acc[2][1] = fmaf(a.z, b.y, acc[2][1]);
    acc[2][2] = fmaf(a.z, b.z, acc[2][2]);
    acc[2][3] = fmaf(a.z, b.w, acc[2][3]);
    acc[3][0] = fmaf(a.w, b.x, acc[3][0]);
    acc[3][1] = fmaf(a.w, b.y, acc[3][1]);
    acc[3][2] = fmaf(a.w, b.z, acc[3][2]);
    acc[3][3] = fmaf(a.w, b.w, acc[3][3]);
}

// ---------------- k0: cos table ----------------
__global__ void k_cos(float* __restrict__ cosT) {
    int i = blockIdx.x, j = threadIdx.x;
    float ang = (float)(i * j) * 3.14159265358979323846f * (1.0f / 64.0f);
    cosT[i * 64 + j] = cosf(ang) * (1.0f / 64.0f);
}

// ---------------- k1: z / silu(z) / wexp (batch-independent) ----------------
__global__ void k_z(const float* __restrict__ freq, const float* __restrict__ g_z,
                    const float* __restrict__ b_z, const float* __restrict__ Wz,
                    const float* __restrict__ bz,
                    float* __restrict__ siluzT, float* __restrict__ wexpT) {
    int hw = blockIdx.x;          // h*64 + w
    int h = hw >> 6, w = hw & 63;
    int c = threadIdx.x;
    float f = freq[hw * 64 + c];
    float s = f;
    #pragma unroll
    for (int off = 32; off > 0; off >>= 1) s += __shfl_xor(s, off, 64);
    float mu = s * (1.0f / 64.0f);
    float d = f - mu;
    float s2 = d * d;
    #pragma unroll
    for (int off = 32; off > 0; off >>= 1) s2 += __shfl_xor(s2, off, 64);
    float var = s2 * (1.0f / 64.0f);
    float xn = d * rsqrtf(var + 1e-5f) * g_z[c] + b_z[c];
    __shared__ float xnS[64];
    xnS[c] = xn;
    __syncthreads();
    float acc = bz[c];
    #pragma unroll 8
    for (int c2 = 0; c2 < 64; ++c2) acc = fmaf(xnS[c2], Wz[c2 * 64 + c], acc);
    float zc = acc;
    siluzT[c * 4096 + hw] = zc / (1.0f + expf(-zc));
    // ln(decay) = -(h+w)/64 - ln(64)
    float lnd = -(float)(h + w) * (1.0f / 64.0f) - 4.1588830833596718565f;
    wexpT[c * 4096 + hw] = expf(zc * lnd);
}

// ---------------- k2: k = LN(x^T + freq) @ Wk + bk ----------------
__global__ __launch_bounds__(256) void k_k(
    const float* __restrict__ x, const float* __restrict__ freq,
    const float* __restrict__ g_k, const float* __restrict__ b_k,
    const float* __restrict__ Wk, const float* __restrict__ bk,
    float* __restrict__ planes) {
    int b = blockIdx.x >> 6, h = blockIdx.x & 63;
    __shared__ __align__(16) float xsT[64][PADR];   // [c][w]
    __shared__ __align__(16) float WkS[64][PADR];   // [c][n]
    __shared__ __align__(16) float red1[4][PADR], red2[4][PADR];
    __shared__ __align__(16) float muS[64], rsS[64];
    int t = threadIdx.x;

    #pragma unroll
    for (int i = 0; i < 4; ++i) {                    // Wk -> LDS (1024 float4 / 256 thr)
        int e = t + i * 256;
        int row = e >> 4, col = (e & 15) << 2;
        *(float4*)&WkS[row][col] = *(const float4*)&Wk[row * 64 + col];
    }
    const float* xb = x + (b * 64 * 64 + h) * 64;    // xb[c*4096 + w]
    const float* fh = freq + h * 4096;               // fh[w*64 + c]
    #pragma unroll
    for (int i = 0; i < 4; ++i) {
        int e = t + i * 256;
        int c = e >> 4, w = (e & 15) << 2;
        float4 xv = *(const float4*)&xb[c * 4096 + w];
        xv.x += fh[(w + 0) * 64 + c];
        xv.y += fh[(w + 1) * 64 + c];
        xv.z += fh[(w + 2) * 64 + c];
        xv.w += fh[(w + 3) * 64 + c];
        *(float4*)&xsT[c][w] = xv;
    }
    __syncthreads();
    {   // LN partial sums over c, per w
        int w = t & 63, q = t >> 6;
        float s1 = 0.f, s2 = 0.f;
        #pragma unroll
        for (int k = 0; k < 16; ++k) { float v = xsT[q * 16 + k][w]; s1 += v; s2 += v * v; }
        red1[q][w] = s1; red2[q][w] = s2;
    }
    __syncthreads();
    if (t < 64) {
        float s1 = red1[0][t] + red1[1][t] + red1[2][t] + red1[3][t];
        float s2 = red2[0][t] + red2[1][t] + red2[2][t] + red2[3][t];
        float mu = s1 * (1.0f / 64.0f);
        float var = s2 * (1.0f / 64.0f) - mu * mu;
        muS[t] = mu; rsS[t] = rsqrtf(var + 1e-5f);
    }
    __syncthreads();
    #pragma unroll
    for (int i = 0; i < 4; ++i) {                    // normalize in place
        int e = t + i * 256;
        int c = e >> 4, w = (e & 15) << 2;
        float gk = g_k[c], bkc = b_k[c];
        float4 v = *(float4*)&xsT[c][w];
        float4 mu = *(const float4*)&muS[w];
        float4 rs = *(const float4*)&rsS[w];
        v.x = (v.x - mu.x) * rs.x * gk + bkc;
        v.y = (v.y - mu.y) * rs.y * gk + bkc;
        v.z = (v.z - mu.z) * rs.z * gk + bkc;
        v.w = (v.w - mu.w) * rs.w * gk + bkc;
        *(float4*)&xsT[c][w] = v;
    }
    __syncthreads();
    // out[w][n] = sum_c xn[w][c] * Wk[c][n] + bk[n]
    int p = t & 15, g = t >> 4;
    int w0 = p << 2, n0 = g << 2;
    float4 bkv = *(const float4*)&bk[n0];
    float acc[4][4];
    #pragma unroll
    for (int i = 0; i < 4; ++i) { acc[i][0] = bkv.x; acc[i][1] = bkv.y; acc[i][2] = bkv.z; acc[i][3] = bkv.w; }
    #pragma unroll 8
    for (int c = 0; c < 64; ++c) {
        float4 a = *(const float4*)&xsT[c][w0];
        float4 bb = *(const float4*)&WkS[c][n0];
        fma16(acc, a, bb);
    }
    #pragma unroll
    for (int j = 0; j < 4; ++j) {
        float4 v = make_float4(acc[0][j], acc[1][j], acc[2][j], acc[3][j]);
        *(float4*)&planes[((b * 64 + n0 + j) * 64 + h) * 64 + w0] = v;   // planes[b][n][h][w]
    }
}

// ---------------- k3: spectral transform per (b,c) plane, in place ----------------
__global__ __launch_bounds__(256) void k_spec(float* __restrict__ planes,
                                              const float* __restrict__ cosT,
                                              const float* __restrict__ wexpT) {
    int b = blockIdx.x >> 6, c = blockIdx.x & 63;
    __shared__ __align__(16) float Cs[64][PADR];
    __shared__ __align__(16) float Pp[64][PADR];
    __shared__ __align__(16) float AT[64][PADR];   // A^T, reused for A2^T
    __shared__ __align__(16) float T2[64][PADR];
    int t = threadIdx.x;
    float* po = planes + (b * 64 + c) * 4096;
    #pragma unroll
    for (int i = 0; i < 4; ++i) {
        int e = t + i * 256;
        int row = e >> 4, col = (e & 15) << 2;
        *(float4*)&Cs[row][col] = *(const float4*)&cosT[row * 64 + col];
        *(float4*)&Pp[row][col] = *(const float4*)&po[row * 64 + col];
    }
    __syncthreads();
    int p = t & 15, g = t >> 4;
    int r0 = p << 2, c0 = g << 2;
    float acc[4][4];

    // M1: A[n][w] = sum_h C[n][h]*P[h][w]   (X^T[h][n]=Cs[h][n] by symmetry)
    #pragma unroll
    for (int i = 0; i < 4; ++i) { acc[i][0]=0.f; acc[i][1]=0.f; acc[i][2]=0.f; acc[i][3]=0.f; }
    #pragma unroll 8
    for (int k = 0; k < 64; ++k) {
        float4 a = *(const float4*)&Cs[k][r0];
        float4 bb = *(const float4*)&Pp[k][c0];
        fma16(acc, a, bb);
    }
    #pragma unroll
    for (int j = 0; j < 4; ++j)
        *(float4*)&AT[c0 + j][r0] = make_float4(acc[0][j], acc[1][j], acc[2][j], acc[3][j]);
    __syncthreads();

    // M2: T2[n][m] = sum_w A[n][w]*C[m][w]  (Y[w][m]=Cs[w][m] by symmetry); gate with wexp
    #pragma unroll
    for (int i = 0; i < 4; ++i) { acc[i][0]=0.f; acc[i][1]=0.f; acc[i][2]=0.f; acc[i][3]=0.f; }
    #pragma unroll 8
    for (int k = 0; k < 64; ++k) {
        float4 a = *(const float4*)&AT[k][r0];
        float4 bb = *(const float4*)&Cs[k][c0];
        fma16(acc, a, bb);
    }
    {
        const float* wx = wexpT + c * 4096;
        #pragma unroll
        for (int i = 0; i < 4; ++i) {
            float4 wv = *(const float4*)&wx[(r0 + i) * 64 + c0];
            *(float4*)&T2[r0 + i][c0] =
                make_float4(acc[i][0] * wv.x, acc[i][1] * wv.y, acc[i][2] * wv.z, acc[i][3] * wv.w);
        }
    }
    __syncthreads();

    // M3: A2[h][m] = sum_n C[n][h]*T2[n][m]
    #pragma unroll
    for (int i = 0; i < 4; ++i) { acc[i][0]=0.f; acc[i][1]=0.f; acc[i][2]=0.f; acc[i][3]=0.f; }
    #pragma unroll 8
    for (int k = 0; k < 64; ++k) {
        float4 a = *(const float4*)&Cs[k][r0];
        float4 bb = *(const float4*)&T2[k][c0];
        fma16(acc, a, bb);
    }
    #pragma unroll
    for (int j = 0; j < 4; ++j)
        *(float4*)&AT[c0 + j][r0] = make_float4(acc[0][j], acc[1][j], acc[2][j], acc[3][j]);  // A2^T
    __syncthreads();

    // M4: P2[h][w] = sum_m A2[h][m]*C[m][w] -> global, in place
    #pragma unroll
    for (int i = 0; i < 4; ++i) { acc[i][0]=0.f; acc[i][1]=0.f; acc[i][2]=0.f; acc[i][3]=0.f; }
    #pragma unroll 8
    for (int k = 0; k < 64; ++k) {
        float4 a = *(const float4*)&AT[k][r0];
        float4 bb = *(const float4*)&Cs[k][c0];
        fma16(acc, a, bb);
    }
    #pragma unroll
    for (int i = 0; i < 4; ++i)
        *(float4*)&po[(r0 + i) * 64 + c0] = make_float4(acc[i][0], acc[i][1], acc[i][2], acc[i][3]);
}

// ---------------- k4: out = (LN(t)*g_o+b_o)*silu(z) @ Wo + bo ----------------
__global__ __launch_bounds__(256) void k_out(
    const float* __restrict__ planes, const float* __restrict__ siluzT,
    const float* __restrict__ g_o, const float* __restrict__ b_o,
    const float* __restrict__ Wo, const float* __restrict__ bo,
    float* __restrict__ out) {
    int b = blockIdx.x >> 6, h = blockIdx.x & 63;
    __shared__ __align__(16) float tsT[64][PADR];   // [c][w]
    __shared__ __align__(16) float WoS[64][PADR];
    __shared__ __align__(16) float red1[4][PADR], red2[4][PADR];
    __shared__ __align__(16) float muS[64], rsS[64];
    int t = threadIdx.x;

    #pragma unroll
    for (int i = 0; i < 4; ++i) {
        int e = t + i * 256;
        int row = e >> 4, col = (e & 15) << 2;
        *(float4*)&WoS[row][col] = *(const float4*)&Wo[row * 64 + col];
    }
    const float* pb = planes + (b * 64 * 64) * 64 + h * 64;  // pb[c*4096 + w]
    #pragma unroll
    for (int i = 0; i < 4; ++i) {
        int e = t + i * 256;
        int c = e >> 4, w = (e & 15) << 2;
        *(float4*)&tsT[c][w] = *(const float4*)&pb[c * 4096 + w];
    }
    __syncthreads();
    {
        int w = t & 63, q = t >> 6;
        float s1 = 0.f, s2 = 0.f;
        #pragma unroll
        for (int k = 0; k < 16; ++k) { float v = tsT[q * 16 + k][w]; s1 += v; s2 += v * v; }
        red1[q][w] = s1; red2[q][w] = s2;
    }
    __syncthreads();
    if (t < 64) {
        float s1 = red1[0][t] + red1[1][t] + red1[2][t] + red1[3][t];
        float s2 = red2[0][t] + red2[1][t] + red2[2][t] + red2[3][t];
        float mu = s1 * (1.0f / 64.0f);
        float var = s2 * (1.0f / 64.0f) - mu * mu;
        muS[t] = mu; rsS[t] = rsqrtf(var + 1e-5f);
    }
    __syncthreads();
    const float* sz = siluzT + h * 64;               // sz[c*4096 + w]
    #pragma unroll
    for (int i = 0; i < 4; ++i) {
        int e = t + i * 256;
        int c = e >> 4, w = (e & 15) << 2;
        float go = g_o[c], boc = b_o[c];
        float4 v = *(float4*)&tsT[c][w];
        float4 mu = *(const float4*)&muS[w];
        float4 rs = *(const float4*)&rsS[w];
        float4 sv = *(const float4*)&sz[c * 4096 + w];
        v.x = ((v.x - mu.x) * rs.x * go + boc) * sv.x;
        v.y = ((v.y - mu.y) * rs.y * go + boc) * sv.y;
        v.z = ((v.z - mu.z) * rs.z * go + boc) * sv.z;
        v.w = ((v.w - mu.w) * rs.w * go + boc) * sv.w;
        *(float4*)&tsT[c][w] = v;
    }
    __syncthreads();
    int p = t & 15, g = t >> 4;
    int w0 = p << 2, o0 = g << 2;
    float4 bov = *(const float4*)&bo[o0];
    float acc[4][4];
    #pragma unroll
    for (int i = 0; i < 4; ++i) { acc[i][0] = bov.x; acc[i][1] = bov.y; acc[i][2] = bov.z; acc[i][3] = bov.w; }
    #pragma unroll 8
    for (int c = 0; c < 64; ++c) {
        float4 a = *(const float4*)&tsT[c][w0];
        float4 bb = *(const float4*)&WoS[c][o0];
        fma16(acc, a, bb);
    }
    #pragma unroll
    for (int j = 0; j < 4; ++j) {
        float4 v = make_float4(acc[0][j], acc[1][j], acc[2][j], acc[3][j]);
        *(float4*)&out[((b * 64 + o0 + j) * 64 + h) * 64 + w0] = v;   // out[b][co][h][w]
    }
}

extern "C" void kernel_launch(void* const* d_in, const int* in_sizes, int n_in,
                              void* d_out, int out_size, void* d_ws, size_t ws_size,
                              hipStream_t stream) {
    const float* x    = (const float*)d_in[0];
    const float* freq = (const float*)d_in[1];
    const float* g_k  = (const float*)d_in[2];
    const float* b_k  = (const float*)d_in[3];
    const float* Wk   = (const float*)d_in[4];
    const float* bk   = (const float*)d_in[5];
    const float* g_z  = (const float*)d_in[6];
    const float* b_z  = (const float*)d_in[7];
    const float* Wz   = (const float*)d_in[8];
    const float* bz   = (const float*)d_in[9];
    const float* g_o  = (const float*)d_in[10];
    const float* b_o  = (const float*)d_in[11];
    const float* Wo   = (const float*)d_in[12];
    const float* bo   = (const float*)d_in[13];
    float* out = (float*)d_out;

    float* ws = (float*)d_ws;
    float* planes = ws;                        // 64^4 = 16777216 floats
    float* siluzT = planes + 16777216;         // (C,H,W) 262144
    float* wexpT  = siluzT + 262144;           // (C,H,W) 262144
    float* cosT   = wexpT + 262144;            // 4096
    // total ~69.2 MB of d_ws

    k_cos<<<64, 64, 0, stream>>>(cosT);
    k_z<<<4096, 64, 0, stream>>>(freq, g_z, b_z, Wz, bz, siluzT, wexpT);
    k_k<<<4096, 256, 0, stream>>>(x, freq, g_k, b_k, Wk, bk, planes);
    k_spec<<<4096, 256, 0, stream>>>(planes, cosT, wexpT);
    k_out<<<4096, 256, 0, stream>>>(planes, siluzT, g_o, b_o, Wo, bo, out);
}

// Round 2
// 241.595 us; speedup vs baseline: 1.3374x; 1.3374x over previous
//
#include <hip/hip_runtime.h>

// Heat2D: B=C=H=W=KD=64.
//   k0: cos table split to bf16 hi/lo (C symmetric)
//   k1: z = LN(freq)@Wz+bz; siluzT[c][h][w], wexpT[c][n][m]
//   k2: per (b,h): LN_c(x^T + freq) @ Wk + bk -> planes[b][n][h][w]   (fp32 VALU)
//   k3: per (b,c): P2 = C*((C*P*C).*wexp)*C via split-bf16 MFMA, in place
//   k4: per (b,h): (LN_c(planes)*g_o+b_o)*siluz @ Wo + bo -> out      (fp32 VALU)

#define PADR 68

typedef __attribute__((ext_vector_type(8))) short short8;
typedef __attribute__((ext_vector_type(4))) float f32x4;
typedef __attribute__((ext_vector_type(4))) unsigned short us4;

__device__ __forceinline__ unsigned short bfhi(float f) {
    return (unsigned short)(__builtin_bit_cast(unsigned int, f) >> 16);
}
__device__ __forceinline__ float hif(float f) {
    return __builtin_bit_cast(float, __builtin_bit_cast(unsigned int, f) & 0xFFFF0000u);
}
// swizzled byte address in a 64x64 bf16 row-major buffer: rows = 128B = 8 chunks
// of 16B; chunk index XOR'd with (row&7) -> bank-uniform b128/b64/u16 access.
__device__ __forceinline__ int swa(int row, int col) {
    return (row << 7) + (((col >> 3) ^ (row & 7)) << 4) + ((col & 7) << 1);
}
__device__ __forceinline__ short8 fragrd(const short* buf, int row, int kc) {
    int a = (row << 7) + (((kc ^ (row & 7)) << 4));
    return *(const short8*)((const char*)buf + a);
}

__device__ __forceinline__ void fma16(float (&acc)[4][4], float4 a, float4 b) {
    acc[0][0] = fmaf(a.x, b.x, acc[0][0]);
    acc[0][1] = fmaf(a.x, b.y, acc[0][1]);
    acc[0][2] = fmaf(a.x, b.z, acc[0][2]);
    acc[0][3] = fmaf(a.x, b.w, acc[0][3]);
    acc[1][0] = fmaf(a.y, b.x, acc[1][0]);
    acc[1][1] = fmaf(a.y, b.y, acc[1][1]);
    acc[1][2] = fmaf(a.y, b.z, acc[1][2]);
    acc[1][3] = fmaf(a.y, b.w, acc[1][3]);
    acc[2][0] = fmaf(a.z, b.x, acc[2][0]);
    acc[2][1] = fmaf(a.z, b.y, acc[2][1]);
    acc[2][2] = fmaf(a.z, b.z, acc[2][2]);
    acc[2][3] = fmaf(a.z, b.w, acc[2][3]);
    acc[3][0] = fmaf(a.w, b.x, acc[3][0]);
    acc[3][1] = fmaf(a.w, b.y, acc[3][1]);
    acc[3][2] = fmaf(a.w, b.z, acc[3][2]);
    acc[3][3] = fmaf(a.w, b.w, acc[3][3]);
}

// ---------------- k0: cos table, split bf16 ----------------
__global__ void k_cos(unsigned short* __restrict__ chi, unsigned short* __restrict__ clo) {
    int i = blockIdx.x, j = threadIdx.x;
    float ang = (float)(i * j) * 3.14159265358979323846f * (1.0f / 64.0f);
    float v = cosf(ang) * (1.0f / 64.0f);
    chi[i * 64 + j] = bfhi(v);
    clo[i * 64 + j] = bfhi(v - hif(v));
}

// ---------------- k1: z / silu(z) / wexp ----------------
__global__ void k_z(const float* __restrict__ freq, const float* __restrict__ g_z,
                    const float* __restrict__ b_z, const float* __restrict__ Wz,
                    const float* __restrict__ bz,
                    float* __restrict__ siluzT, float* __restrict__ wexpT) {
    int hw = blockIdx.x;
    int h = hw >> 6, w = hw & 63;
    int c = threadIdx.x;
    float f = freq[hw * 64 + c];
    float s = f;
    #pragma unroll
    for (int off = 32; off > 0; off >>= 1) s += __shfl_xor(s, off, 64);
    float mu = s * (1.0f / 64.0f);
    float d = f - mu;
    float s2 = d * d;
    #pragma unroll
    for (int off = 32; off > 0; off >>= 1) s2 += __shfl_xor(s2, off, 64);
    float var = s2 * (1.0f / 64.0f);
    float xn = d * rsqrtf(var + 1e-5f) * g_z[c] + b_z[c];
    __shared__ float xnS[64];
    xnS[c] = xn;
    __syncthreads();
    float acc = bz[c];
    #pragma unroll 8
    for (int c2 = 0; c2 < 64; ++c2) acc = fmaf(xnS[c2], Wz[c2 * 64 + c], acc);
    float zc = acc;
    siluzT[c * 4096 + hw] = zc / (1.0f + expf(-zc));
    float lnd = -(float)(h + w) * (1.0f / 64.0f) - 4.1588830833596718565f;
    wexpT[c * 4096 + hw] = expf(zc * lnd);
}

// ---------------- k2: k = LN(x^T + freq) @ Wk + bk ----------------
__global__ __launch_bounds__(256) void k_k(
    const float* __restrict__ x, const float* __restrict__ freq,
    const float* __restrict__ g_k, const float* __restrict__ b_k,
    const float* __restrict__ Wk, const float* __restrict__ bk,
    float* __restrict__ planes) {
    int b = blockIdx.x >> 6, h = blockIdx.x & 63;
    __shared__ __align__(16) float xsT[64][PADR];
    __shared__ __align__(16) float WkS[64][PADR];
    __shared__ __align__(16) float red1[4][PADR], red2[4][PADR];
    __shared__ __align__(16) float muS[64], rsS[64];
    int t = threadIdx.x;

    #pragma unroll
    for (int i = 0; i < 4; ++i) {
        int e = t + i * 256;
        int row = e >> 4, col = (e & 15) << 2;
        *(float4*)&WkS[row][col] = *(const float4*)&Wk[row * 64 + col];
    }
    const float* xb = x + (b * 64 * 64 + h) * 64;
    const float* fh = freq + h * 4096;
    #pragma unroll
    for (int i = 0; i < 4; ++i) {
        int e = t + i * 256;
        int c = e >> 4, w = (e & 15) << 2;
        float4 xv = *(const float4*)&xb[c * 4096 + w];
        xv.x += fh[(w + 0) * 64 + c];
        xv.y += fh[(w + 1) * 64 + c];
        xv.z += fh[(w + 2) * 64 + c];
        xv.w += fh[(w + 3) * 64 + c];
        *(float4*)&xsT[c][w] = xv;
    }
    __syncthreads();
    {
        int w = t & 63, q = t >> 6;
        float s1 = 0.f, s2 = 0.f;
        #pragma unroll
        for (int k = 0; k < 16; ++k) { float v = xsT[q * 16 + k][w]; s1 += v; s2 += v * v; }
        red1[q][w] = s1; red2[q][w] = s2;
    }
    __syncthreads();
    if (t < 64) {
        float s1 = red1[0][t] + red1[1][t] + red1[2][t] + red1[3][t];
        float s2 = red2[0][t] + red2[1][t] + red2[2][t] + red2[3][t];
        float mu = s1 * (1.0f / 64.0f);
        float var = s2 * (1.0f / 64.0f) - mu * mu;
        muS[t] = mu; rsS[t] = rsqrtf(var + 1e-5f);
    }
    __syncthreads();
    #pragma unroll
    for (int i = 0; i < 4; ++i) {
        int e = t + i * 256;
        int c = e >> 4, w = (e & 15) << 2;
        float gk = g_k[c], bkc = b_k[c];
        float4 v = *(float4*)&xsT[c][w];
        float4 mu = *(const float4*)&muS[w];
        float4 rs = *(const float4*)&rsS[w];
        v.x = (v.x - mu.x) * rs.x * gk + bkc;
        v.y = (v.y - mu.y) * rs.y * gk + bkc;
        v.z = (v.z - mu.z) * rs.z * gk + bkc;
        v.w = (v.w - mu.w) * rs.w * gk + bkc;
        *(float4*)&xsT[c][w] = v;
    }
    __syncthreads();
    int p = t & 15, g = t >> 4;
    int w0 = p << 2, n0 = g << 2;
    float4 bkv = *(const float4*)&bk[n0];
    float acc[4][4];
    #pragma unroll
    for (int i = 0; i < 4; ++i) { acc[i][0] = bkv.x; acc[i][1] = bkv.y; acc[i][2] = bkv.z; acc[i][3] = bkv.w; }
    #pragma unroll 8
    for (int c = 0; c < 64; ++c) {
        float4 a = *(const float4*)&xsT[c][w0];
        float4 bb = *(const float4*)&WkS[c][n0];
        fma16(acc, a, bb);
    }
    #pragma unroll
    for (int j = 0; j < 4; ++j) {
        float4 v = make_float4(acc[0][j], acc[1][j], acc[2][j], acc[3][j]);
        *(float4*)&planes[((b * 64 + n0 + j) * 64 + h) * 64 + w0] = v;
    }
}

// ---------------- k3: spectral transform, split-bf16 MFMA ----------------
// Per block: one (b,c) plane, 4 waves, each computes a 32x32 quadrant (2x2
// tiles of 16x16) per stage. Buffers row-major bf16 (hi/lo), XOR-swizzled.
// Stage outputs (C/D layout: col=lane&15, row=quad*4+r) are written back
// TRANSPOSED as packed b64 (4 consecutive cols), which lands them row-major
// for the next stage's operand role; M3 writes row-major via u16 scatter.
__global__ __launch_bounds__(256, 3) void k_spec(
    float* __restrict__ planes,
    const unsigned short* __restrict__ cos_hi, const unsigned short* __restrict__ cos_lo,
    const float* __restrict__ wexpT) {
    __shared__ short Ch[4096], Cl[4096];
    __shared__ short D0h[4096], D0l[4096];
    __shared__ short D1h[4096], D1l[4096];
    int b = blockIdx.x >> 6, c = blockIdx.x & 63;
    float* po = planes + (b * 64 + c) * 4096;
    int t = threadIdx.x;
    int lane = t & 63, wv = t >> 6;
    int q = lane >> 4, l15 = lane & 15;
    int m0 = (wv & 1) << 5, n0 = (wv >> 1) << 5;

    // stage cos hi/lo (swizzled)
    {
        int r = t >> 2, cb = (t & 3) << 4;
        #pragma unroll
        for (int p = 0; p < 2; ++p) {
            int chunk = (cb >> 3) + p;
            int a = (r << 7) + (((chunk ^ (r & 7)) << 4));
            *(uint4*)((char*)Ch + a) = *(const uint4*)&cos_hi[r * 64 + cb + p * 8];
            *(uint4*)((char*)Cl + a) = *(const uint4*)&cos_lo[r * 64 + cb + p * 8];
        }
    }
    // stage P^T into D0: rows = w, cols = h (per-thread column of P)
    {
        int w = t & 63, h0 = (t >> 6) << 4;
        float v[16];
        #pragma unroll
        for (int j = 0; j < 16; ++j) v[j] = po[(h0 + j) * 64 + w];
        #pragma unroll
        for (int g = 0; g < 4; ++g) {
            int col = h0 + (g << 2);
            int a = swa(w, col);
            us4 hv, lv;
            #pragma unroll
            for (int r = 0; r < 4; ++r) {
                float f = v[(g << 2) + r];
                hv[r] = bfhi(f);
                lv[r] = bfhi(f - hif(f));
            }
            *(us4*)((char*)D0h + a) = hv;
            *(us4*)((char*)D0l + a) = lv;
        }
    }
    __syncthreads();

    f32x4 acc[2][2];
    const f32x4 zero = {0.f, 0.f, 0.f, 0.f};

#define MM(Ah, Al, Bh, Bl)                                                          \
    {                                                                               \
        acc[0][0] = zero; acc[0][1] = zero; acc[1][0] = zero; acc[1][1] = zero;     \
        _Pragma("unroll")                                                           \
        for (int kb = 0; kb < 2; ++kb) {                                            \
            int kc = (kb << 2) + q;                                                 \
            short8 a0h = fragrd(Ah, m0 + l15, kc);                                  \
            short8 a0l = fragrd(Al, m0 + l15, kc);                                  \
            short8 a1h = fragrd(Ah, m0 + 16 + l15, kc);                             \
            short8 a1l = fragrd(Al, m0 + 16 + l15, kc);                             \
            short8 b0h = fragrd(Bh, n0 + l15, kc);                                  \
            short8 b0l = fragrd(Bl, n0 + l15, kc);                                  \
            short8 b1h = fragrd(Bh, n0 + 16 + l15, kc);                             \
            short8 b1l = fragrd(Bl, n0 + 16 + l15, kc);                             \
            acc[0][0] = __builtin_amdgcn_mfma_f32_16x16x32_bf16(a0h, b0h, acc[0][0], 0, 0, 0); \
            acc[0][0] = __builtin_amdgcn_mfma_f32_16x16x32_bf16(a0h, b0l, acc[0][0], 0, 0, 0); \
            acc[0][0] = __builtin_amdgcn_mfma_f32_16x16x32_bf16(a0l, b0h, acc[0][0], 0, 0, 0); \
            acc[0][1] = __builtin_amdgcn_mfma_f32_16x16x32_bf16(a0h, b1h, acc[0][1], 0, 0, 0); \
            acc[0][1] = __builtin_amdgcn_mfma_f32_16x16x32_bf16(a0h, b1l, acc[0][1], 0, 0, 0); \
            acc[0][1] = __builtin_amdgcn_mfma_f32_16x16x32_bf16(a0l, b1h, acc[0][1], 0, 0, 0); \
            acc[1][0] = __builtin_amdgcn_mfma_f32_16x16x32_bf16(a1h, b0h, acc[1][0], 0, 0, 0); \
            acc[1][0] = __builtin_amdgcn_mfma_f32_16x16x32_bf16(a1h, b0l, acc[1][0], 0, 0, 0); \
            acc[1][0] = __builtin_amdgcn_mfma_f32_16x16x32_bf16(a1l, b0h, acc[1][0], 0, 0, 0); \
            acc[1][1] = __builtin_amdgcn_mfma_f32_16x16x32_bf16(a1h, b1h, acc[1][1], 0, 0, 0); \
            acc[1][1] = __builtin_amdgcn_mfma_f32_16x16x32_bf16(a1h, b1l, acc[1][1], 0, 0, 0); \
            acc[1][1] = __builtin_amdgcn_mfma_f32_16x16x32_bf16(a1l, b1h, acc[1][1], 0, 0, 0); \
        }                                                                           \
    }

#define WB_T(Dh, Dl)                                                                \
    {                                                                               \
        _Pragma("unroll")                                                           \
        for (int ti = 0; ti < 2; ++ti)                                              \
            _Pragma("unroll")                                                       \
            for (int u = 0; u < 2; ++u) {                                           \
                int row = n0 + (u << 4) + l15;                                      \
                int col = m0 + (ti << 4) + (q << 2);                                \
                int a = swa(row, col);                                              \
                us4 hv, lv;                                                         \
                _Pragma("unroll")                                                   \
                for (int r = 0; r < 4; ++r) {                                       \
                    float f = acc[ti][u][r];                                        \
                    hv[r] = bfhi(f);                                                \
                    lv[r] = bfhi(f - hif(f));                                       \
                }                                                                   \
                *(us4*)((char*)Dh + a) = hv;                                        \
                *(us4*)((char*)Dl + a) = lv;                                        \
            }                                                                       \
    }

    // M1: D = P^T * C = A1^T  (A=P^T in D0, B^T=C); transposed WB -> A1 row-major in D1
    MM(D0h, D0l, Ch, Cl)
    WB_T(D1h, D1l)
    __syncthreads();

    // M2: D = A1 * C = T[n][m]  (A=A1 in D1, B^T=C); gate; transposed WB -> T'^T in D0
    MM(D1h, D1l, Ch, Cl)
    {
        const float* wx = wexpT + c * 4096;
        #pragma unroll
        for (int ti = 0; ti < 2; ++ti)
            #pragma unroll
            for (int u = 0; u < 2; ++u)
                #pragma unroll
                for (int r = 0; r < 4; ++r) {
                    int n = m0 + (ti << 4) + (q << 2) + r;
                    int m = n0 + (u << 4) + l15;
                    acc[ti][u][r] *= wx[n * 64 + m];
                }
    }
    WB_T(D0h, D0l)
    __syncthreads();

    // M3: D = C * T' = A2[h][m]  (A=C, B^T=T'^T in D0); ROW-major WB (u16) -> D1
    MM(Ch, Cl, D0h, D0l)
    {
        #pragma unroll
        for (int ti = 0; ti < 2; ++ti)
            #pragma unroll
            for (int u = 0; u < 2; ++u)
                #pragma unroll
                for (int r = 0; r < 4; ++r) {
                    int row = m0 + (ti << 4) + (q << 2) + r;
                    int col = n0 + (u << 4) + l15;
                    int a = swa(row, col);
                    float f = acc[ti][u][r];
                    *(unsigned short*)((char*)D1h + a) = bfhi(f);
                    *(unsigned short*)((char*)D1l + a) = bfhi(f - hif(f));
                }
    }
    __syncthreads();

    // M4: D = A2 * C = P2[h][w]  (A=A2 in D1, B^T=C) -> global, in place
    MM(D1h, D1l, Ch, Cl)
    {
        #pragma unroll
        for (int ti = 0; ti < 2; ++ti)
            #pragma unroll
            for (int u = 0; u < 2; ++u)
                #pragma unroll
                for (int r = 0; r < 4; ++r) {
                    int h = m0 + (ti << 4) + (q << 2) + r;
                    int w = n0 + (u << 4) + l15;
                    po[h * 64 + w] = acc[ti][u][r];
                }
    }
#undef MM
#undef WB_T
}

// ---------------- k4: out = (LN(t)*g_o+b_o)*silu(z) @ Wo + bo ----------------
__global__ __launch_bounds__(256) void k_out(
    const float* __restrict__ planes, const float* __restrict__ siluzT,
    const float* __restrict__ g_o, const float* __restrict__ b_o,
    const float* __restrict__ Wo, const float* __restrict__ bo,
    float* __restrict__ out) {
    int b = blockIdx.x >> 6, h = blockIdx.x & 63;
    __shared__ __align__(16) float tsT[64][PADR];
    __shared__ __align__(16) float WoS[64][PADR];
    __shared__ __align__(16) float red1[4][PADR], red2[4][PADR];
    __shared__ __align__(16) float muS[64], rsS[64];
    int t = threadIdx.x;

    #pragma unroll
    for (int i = 0; i < 4; ++i) {
        int e = t + i * 256;
        int row = e >> 4, col = (e & 15) << 2;
        *(float4*)&WoS[row][col] = *(const float4*)&Wo[row * 64 + col];
    }
    const float* pb = planes + (b * 64 * 64) * 64 + h * 64;
    #pragma unroll
    for (int i = 0; i < 4; ++i) {
        int e = t + i * 256;
        int c = e >> 4, w = (e & 15) << 2;
        *(float4*)&tsT[c][w] = *(const float4*)&pb[c * 4096 + w];
    }
    __syncthreads();
    {
        int w = t & 63, q = t >> 6;
        float s1 = 0.f, s2 = 0.f;
        #pragma unroll
        for (int k = 0; k < 16; ++k) { float v = tsT[q * 16 + k][w]; s1 += v; s2 += v * v; }
        red1[q][w] = s1; red2[q][w] = s2;
    }
    __syncthreads();
    if (t < 64) {
        float s1 = red1[0][t] + red1[1][t] + red1[2][t] + red1[3][t];
        float s2 = red2[0][t] + red2[1][t] + red2[2][t] + red2[3][t];
        float mu = s1 * (1.0f / 64.0f);
        float var = s2 * (1.0f / 64.0f) - mu * mu;
        muS[t] = mu; rsS[t] = rsqrtf(var + 1e-5f);
    }
    __syncthreads();
    const float* sz = siluzT + h * 64;
    #pragma unroll
    for (int i = 0; i < 4; ++i) {
        int e = t + i * 256;
        int c = e >> 4, w = (e & 15) << 2;
        float go = g_o[c], boc = b_o[c];
        float4 v = *(float4*)&tsT[c][w];
        float4 mu = *(const float4*)&muS[w];
        float4 rs = *(const float4*)&rsS[w];
        float4 sv = *(const float4*)&sz[c * 4096 + w];
        v.x = ((v.x - mu.x) * rs.x * go + boc) * sv.x;
        v.y = ((v.y - mu.y) * rs.y * go + boc) * sv.y;
        v.z = ((v.z - mu.z) * rs.z * go + boc) * sv.z;
        v.w = ((v.w - mu.w) * rs.w * go + boc) * sv.w;
        *(float4*)&tsT[c][w] = v;
    }
    __syncthreads();
    int p = t & 15, g = t >> 4;
    int w0 = p << 2, o0 = g << 2;
    float4 bov = *(const float4*)&bo[o0];
    float acc[4][4];
    #pragma unroll
    for (int i = 0; i < 4; ++i) { acc[i][0] = bov.x; acc[i][1] = bov.y; acc[i][2] = bov.z; acc[i][3] = bov.w; }
    #pragma unroll 8
    for (int c = 0; c < 64; ++c) {
        float4 a = *(const float4*)&tsT[c][w0];
        float4 bb = *(const float4*)&WoS[c][o0];
        fma16(acc, a, bb);
    }
    #pragma unroll
    for (int j = 0; j < 4; ++j) {
        float4 v = make_float4(acc[0][j], acc[1][j], acc[2][j], acc[3][j]);
        *(float4*)&out[((b * 64 + o0 + j) * 64 + h) * 64 + w0] = v;
    }
}

extern "C" void kernel_launch(void* const* d_in, const int* in_sizes, int n_in,
                              void* d_out, int out_size, void* d_ws, size_t ws_size,
                              hipStream_t stream) {
    const float* x    = (const float*)d_in[0];
    const float* freq = (const float*)d_in[1];
    const float* g_k  = (const float*)d_in[2];
    const float* b_k  = (const float*)d_in[3];
    const float* Wk   = (const float*)d_in[4];
    const float* bk   = (const float*)d_in[5];
    const float* g_z  = (const float*)d_in[6];
    const float* b_z  = (const float*)d_in[7];
    const float* Wz   = (const float*)d_in[8];
    const float* bz   = (const float*)d_in[9];
    const float* g_o  = (const float*)d_in[10];
    const float* b_o  = (const float*)d_in[11];
    const float* Wo   = (const float*)d_in[12];
    const float* bo   = (const float*)d_in[13];
    float* out = (float*)d_out;

    float* ws = (float*)d_ws;
    float* planes = ws;                               // 64^4 floats
    float* siluzT = planes + 16777216;                // (C,H,W)
    float* wexpT  = siluzT + 262144;                  // (C,H,W)
    unsigned short* cos_hi = (unsigned short*)(wexpT + 262144);  // 4096 u16
    unsigned short* cos_lo = cos_hi + 4096;

    k_cos<<<64, 64, 0, stream>>>(cos_hi, cos_lo);
    k_z<<<4096, 64, 0, stream>>>(freq, g_z, b_z, Wz, bz, siluzT, wexpT);
    k_k<<<4096, 256, 0, stream>>>(x, freq, g_k, b_k, Wk, bk, planes);
    k_spec<<<4096, 256, 0, stream>>>(planes, cos_hi, cos_lo, wexpT);
    k_out<<<4096, 256, 0, stream>>>(planes, siluzT, g_o, b_o, Wo, bo, out);
}

// Round 3
// 210.651 us; speedup vs baseline: 1.5338x; 1.1469x over previous
//
#include <hip/hip_runtime.h>

// Heat2D: B=C=H=W=KD=64. All big matmuls via split-bf16 (hi/lo) MFMA,
// LN folded into matmul epilogues where possible.
//   k_pre1: transposed split-bf16 weights (g*Wk)^T, (g*Wz)^T, Wo^T; su/v
//           LN-fold vectors; cos table split bf16.
//   k_pre2: z = LN(freq)@Wz+bz via MFMA (LN folded) -> siluzT/wexpT [c][h][w];
//           freqT[c][h][w] transpose.
//   k_k:    per (b,h): LN_c(x^T+freq)@Wk' (LN folded) -> planes[b][n][h][w]
//   k_spec: per (b,c): P2 = C*((C*P*C).*wexp)*C, in place (proven, unchanged)
//   k_out:  per (b,h): ((LN_c(planes)*g_o+b_o)*siluz)@Wo + bo -> out BCHW

typedef __attribute__((ext_vector_type(8))) short short8;
typedef __attribute__((ext_vector_type(4))) float f32x4;
typedef __attribute__((ext_vector_type(4))) unsigned short us4;

__device__ __forceinline__ unsigned short bfhi(float f) {
    return (unsigned short)(__builtin_bit_cast(unsigned int, f) >> 16);
}
__device__ __forceinline__ float hif(float f) {
    return __builtin_bit_cast(float, __builtin_bit_cast(unsigned int, f) & 0xFFFF0000u);
}
// swizzled byte address in 64x64 bf16 row-major buffer (128B rows, 16B chunks
// XOR'd with row&7): bank-uniform for b128 frag reads and b64/u16 writes.
__device__ __forceinline__ int swa(int row, int col) {
    return (row << 7) + (((col >> 3) ^ (row & 7)) << 4) + ((col & 7) << 1);
}
__device__ __forceinline__ short8 fragrd(const short* buf, int row, int kc) {
    int a = (row << 7) + ((kc ^ (row & 7)) << 4);
    return *(const short8*)((const char*)buf + a);
}

// 64x64x64 matmul, 4 waves: wave computes 32x32 quadrant (2x2 16x16 tiles).
// D[m][n] = sum_k A[m][k]*B^T[n][k], 3-term split-bf16 (hh + hl + lh).
__device__ __forceinline__ void mm_block(const short* Ah, const short* Al,
                                         const short* Bh, const short* Bl,
                                         int m0, int n0, int l15, int q,
                                         f32x4 (&acc)[2][2]) {
    const f32x4 zero = {0.f, 0.f, 0.f, 0.f};
    acc[0][0] = zero; acc[0][1] = zero; acc[1][0] = zero; acc[1][1] = zero;
    #pragma unroll
    for (int kb = 0; kb < 2; ++kb) {
        int kc = (kb << 2) + q;
        short8 a0h = fragrd(Ah, m0 + l15, kc);
        short8 a0l = fragrd(Al, m0 + l15, kc);
        short8 a1h = fragrd(Ah, m0 + 16 + l15, kc);
        short8 a1l = fragrd(Al, m0 + 16 + l15, kc);
        short8 b0h = fragrd(Bh, n0 + l15, kc);
        short8 b0l = fragrd(Bl, n0 + l15, kc);
        short8 b1h = fragrd(Bh, n0 + 16 + l15, kc);
        short8 b1l = fragrd(Bl, n0 + 16 + l15, kc);
        acc[0][0] = __builtin_amdgcn_mfma_f32_16x16x32_bf16(a0h, b0h, acc[0][0], 0, 0, 0);
        acc[0][0] = __builtin_amdgcn_mfma_f32_16x16x32_bf16(a0h, b0l, acc[0][0], 0, 0, 0);
        acc[0][0] = __builtin_amdgcn_mfma_f32_16x16x32_bf16(a0l, b0h, acc[0][0], 0, 0, 0);
        acc[0][1] = __builtin_amdgcn_mfma_f32_16x16x32_bf16(a0h, b1h, acc[0][1], 0, 0, 0);
        acc[0][1] = __builtin_amdgcn_mfma_f32_16x16x32_bf16(a0h, b1l, acc[0][1], 0, 0, 0);
        acc[0][1] = __builtin_amdgcn_mfma_f32_16x16x32_bf16(a0l, b1h, acc[0][1], 0, 0, 0);
        acc[1][0] = __builtin_amdgcn_mfma_f32_16x16x32_bf16(a1h, b0h, acc[1][0], 0, 0, 0);
        acc[1][0] = __builtin_amdgcn_mfma_f32_16x16x32_bf16(a1h, b0l, acc[1][0], 0, 0, 0);
        acc[1][0] = __builtin_amdgcn_mfma_f32_16x16x32_bf16(a1l, b0h, acc[1][0], 0, 0, 0);
        acc[1][1] = __builtin_amdgcn_mfma_f32_16x16x32_bf16(a1h, b1h, acc[1][1], 0, 0, 0);
        acc[1][1] = __builtin_amdgcn_mfma_f32_16x16x32_bf16(a1h, b1l, acc[1][1], 0, 0, 0);
        acc[1][1] = __builtin_amdgcn_mfma_f32_16x16x32_bf16(a1l, b1h, acc[1][1], 0, 0, 0);
    }
}

// ---------------- k_pre1: weights transpose/split + LN-fold vectors + cos ----------------
__global__ __launch_bounds__(256) void k_pre1(
    const float* __restrict__ g_k, const float* __restrict__ b_k,
    const float* __restrict__ Wk, const float* __restrict__ bk,
    const float* __restrict__ g_z, const float* __restrict__ b_z,
    const float* __restrict__ Wz, const float* __restrict__ bz,
    const float* __restrict__ Wo,
    unsigned short* __restrict__ WkTh, unsigned short* __restrict__ WkTl,
    float* __restrict__ su_k, float* __restrict__ v_k,
    unsigned short* __restrict__ WzTh, unsigned short* __restrict__ WzTl,
    float* __restrict__ su_z, float* __restrict__ v_z,
    unsigned short* __restrict__ WoTh, unsigned short* __restrict__ WoTl,
    unsigned short* __restrict__ cos_hi, unsigned short* __restrict__ cos_lo) {
    int t = threadIdx.x;
    if (blockIdx.x < 16) {
        int n = blockIdx.x * 4 + (t >> 6);
        int c = t & 63;
        // Wk' = g_k*Wk
        float wk = Wk[c * 64 + n];
        float a = g_k[c] * wk;
        WkTh[n * 64 + c] = bfhi(a);
        WkTl[n * 64 + c] = bfhi(a - hif(a));
        float sa = a, sv = b_k[c] * wk;
        #pragma unroll
        for (int off = 32; off > 0; off >>= 1) {
            sa += __shfl_xor(sa, off, 64);
            sv += __shfl_xor(sv, off, 64);
        }
        if (c == 0) { su_k[n] = sa; v_k[n] = sv + bk[n]; }
        // Wz' = g_z*Wz
        float wz = Wz[c * 64 + n];
        float az = g_z[c] * wz;
        WzTh[n * 64 + c] = bfhi(az);
        WzTl[n * 64 + c] = bfhi(az - hif(az));
        float saz = az, svz = b_z[c] * wz;
        #pragma unroll
        for (int off = 32; off > 0; off >>= 1) {
            saz += __shfl_xor(saz, off, 64);
            svz += __shfl_xor(svz, off, 64);
        }
        if (c == 0) { su_z[n] = saz; v_z[n] = svz + bz[n]; }
        // Wo^T
        float wo = Wo[c * 64 + n];
        WoTh[n * 64 + c] = bfhi(wo);
        WoTl[n * 64 + c] = bfhi(wo - hif(wo));
    } else {
        int idx = (blockIdx.x - 16) * 256 + t;
        int i = idx >> 6, j = idx & 63;
        float ang = (float)(i * j) * 3.14159265358979323846f * (1.0f / 64.0f);
        float v = cosf(ang) * (1.0f / 64.0f);
        cos_hi[idx] = bfhi(v);
        cos_lo[idx] = bfhi(v - hif(v));
    }
}

// ---------------- k_pre2: z via MFMA (LN folded) + freq transpose ----------------
__global__ __launch_bounds__(256) void k_pre2(
    const float* __restrict__ freq,
    const unsigned short* __restrict__ WzTh_g, const unsigned short* __restrict__ WzTl_g,
    const float* __restrict__ su_z, const float* __restrict__ v_z,
    float* __restrict__ siluzT, float* __restrict__ wexpT,
    float* __restrict__ freqT) {
    __shared__ short Ah[4096], Al[4096], Bh[4096], Bl[4096];
    __shared__ float muS[64], rsS[64];
    __shared__ float tile[64][65];
    int t = threadIdx.x;
    if (blockIdx.x < 64) {
        int h = blockIdx.x;
        // stage B = WzT' swizzled
        #pragma unroll
        for (int p = 0; p < 2; ++p) {
            int e = t + p * 256;
            int row = e >> 3, ch = e & 7;
            int a = (row << 7) + (((ch ^ (row & 7)) << 4));
            *(uint4*)((char*)Bh + a) = *(const uint4*)&WzTh_g[row * 64 + ch * 8];
            *(uint4*)((char*)Bl + a) = *(const uint4*)&WzTl_g[row * 64 + ch * 8];
        }
        // A = freq[h][w][c] (already [w][c] row-major). thread: w=t>>2, 16 c's.
        int w = t >> 2, c0 = (t & 3) << 4;
        float4 fr[4];
        float s1 = 0.f, s2 = 0.f;
        #pragma unroll
        for (int i = 0; i < 4; ++i) {
            fr[i] = *(const float4*)&freq[(h * 64 + w) * 64 + c0 + 4 * i];
            s1 += fr[i].x + fr[i].y + fr[i].z + fr[i].w;
            s2 += fr[i].x * fr[i].x + fr[i].y * fr[i].y + fr[i].z * fr[i].z + fr[i].w * fr[i].w;
        }
        s1 += __shfl_xor(s1, 1, 64); s1 += __shfl_xor(s1, 2, 64);
        s2 += __shfl_xor(s2, 1, 64); s2 += __shfl_xor(s2, 2, 64);
        float mu = s1 * (1.0f / 64.0f);
        float var = s2 * (1.0f / 64.0f) - mu * mu;
        float rs = rsqrtf(var + 1e-5f);
        if ((t & 3) == 0) { muS[w] = mu; rsS[w] = rs; }
        const float* fp = (const float*)fr;
        #pragma unroll
        for (int i = 0; i < 4; ++i) {
            us4 hv, lv;
            #pragma unroll
            for (int r = 0; r < 4; ++r) {
                float f = fp[i * 4 + r];
                hv[r] = bfhi(f);
                lv[r] = bfhi(f - hif(f));
            }
            int a = swa(w, c0 + 4 * i);
            *(us4*)((char*)Ah + a) = hv;
            *(us4*)((char*)Al + a) = lv;
        }
        __syncthreads();
        int lane = t & 63, wv = t >> 6;
        int q = lane >> 4, l15 = lane & 15;
        int m0 = (wv & 1) << 5, n0 = (wv >> 1) << 5;
        f32x4 acc[2][2];
        mm_block(Ah, Al, Bh, Bl, m0, n0, l15, q, acc);
        #pragma unroll
        for (int u = 0; u < 2; ++u) {
            int c = n0 + (u << 4) + l15;
            float suc = su_z[c], vc = v_z[c];
            #pragma unroll
            for (int ti = 0; ti < 2; ++ti) {
                int wb = m0 + (ti << 4) + (q << 2);
                float4 mu4 = *(const float4*)&muS[wb];
                float4 rs4 = *(const float4*)&rsS[wb];
                float4 sil, wx;
                #pragma unroll
                for (int r = 0; r < 4; ++r) {
                    float z = ((const float*)&rs4)[r] * (acc[ti][u][r] - ((const float*)&mu4)[r] * suc) + vc;
                    float lnd = -(float)(h + wb + r) * 0.015625f - 4.1588830833596718565f;
                    ((float*)&sil)[r] = z / (1.0f + expf(-z));
                    ((float*)&wx)[r] = expf(z * lnd);
                }
                int base = (c * 64 + h) * 64 + wb;
                *(float4*)&siluzT[base] = sil;
                *(float4*)&wexpT[base] = wx;
            }
        }
    } else {
        // freq transpose: freqT[c][h][w] = freq[h][w][c]
        int h = blockIdx.x - 64;
        int w = t >> 2, c0 = (t & 3) << 4;
        #pragma unroll
        for (int i = 0; i < 4; ++i)
            *(float4*)&tile[w][c0 + 4 * i] = *(const float4*)&freq[(h * 64 + w) * 64 + c0 + 4 * i];
        __syncthreads();
        int w0 = (t & 15) << 2;
        #pragma unroll
        for (int p = 0; p < 4; ++p) {
            int c = (t >> 4) + 16 * p;
            float4 fv = make_float4(tile[w0][c], tile[w0 + 1][c], tile[w0 + 2][c], tile[w0 + 3][c]);
            *(float4*)&freqT[(c * 64 + h) * 64 + w0] = fv;
        }
    }
}

// ---------------- k_k: planes = LN(x^T+freq)@Wk'+... (LN folded, MFMA) ----------------
__global__ __launch_bounds__(256, 3) void k_k(
    const float* __restrict__ x, const float* __restrict__ freqT,
    const unsigned short* __restrict__ WkTh_g, const unsigned short* __restrict__ WkTl_g,
    const float* __restrict__ su_k, const float* __restrict__ v_k,
    float* __restrict__ planes) {
    __shared__ short Ah[4096], Al[4096], Bh[4096], Bl[4096];
    __shared__ __align__(16) float red1[16][68], red2[16][68];
    __shared__ float muS[64], rsS[64];
    int b = blockIdx.x >> 6, h = blockIdx.x & 63;
    int t = threadIdx.x;
    #pragma unroll
    for (int p = 0; p < 2; ++p) {
        int e = t + p * 256;
        int row = e >> 3, ch = e & 7;
        int a = (row << 7) + (((ch ^ (row & 7)) << 4));
        *(uint4*)((char*)Bh + a) = *(const uint4*)&WkTh_g[row * 64 + ch * 8];
        *(uint4*)((char*)Bl + a) = *(const uint4*)&WkTl_g[row * 64 + ch * 8];
    }
    // load xin = x + freqT (both [c][w] rows, coalesced); thread: 4c x 4w block
    int g = t >> 4, w0 = (t & 15) << 2, c0 = g << 2;
    const float* xb = x + (size_t)b * 262144 + h * 64;
    float4 vr[4];
    float4 s1 = {0,0,0,0}, s2 = {0,0,0,0};
    #pragma unroll
    for (int i = 0; i < 4; ++i) {
        int c = c0 + i;
        float4 xv = *(const float4*)&xb[c * 4096 + w0];
        float4 fv = *(const float4*)&freqT[c * 4096 + h * 64 + w0];
        xv.x += fv.x; xv.y += fv.y; xv.z += fv.z; xv.w += fv.w;
        vr[i] = xv;
        s1.x += xv.x; s1.y += xv.y; s1.z += xv.z; s1.w += xv.w;
        s2.x += xv.x * xv.x; s2.y += xv.y * xv.y; s2.z += xv.z * xv.z; s2.w += xv.w * xv.w;
    }
    // split + transpose-write A = xinT[w][c]
    const float* vp = (const float*)vr;
    #pragma unroll
    for (int j = 0; j < 4; ++j) {
        us4 hv, lv;
        #pragma unroll
        for (int r = 0; r < 4; ++r) {
            float f = vp[r * 4 + j];
            hv[r] = bfhi(f);
            lv[r] = bfhi(f - hif(f));
        }
        int a = swa(w0 + j, c0);
        *(us4*)((char*)Ah + a) = hv;
        *(us4*)((char*)Al + a) = lv;
    }
    *(float4*)&red1[g][w0] = s1;
    *(float4*)&red2[g][w0] = s2;
    __syncthreads();
    if (t < 64) {
        float a1 = 0.f, a2 = 0.f;
        #pragma unroll
        for (int j = 0; j < 16; ++j) { a1 += red1[j][t]; a2 += red2[j][t]; }
        float mu = a1 * (1.0f / 64.0f);
        float var = a2 * (1.0f / 64.0f) - mu * mu;
        muS[t] = mu; rsS[t] = rsqrtf(var + 1e-5f);
    }
    __syncthreads();
    int lane = t & 63, wv = t >> 6;
    int q = lane >> 4, l15 = lane & 15;
    int m0 = (wv & 1) << 5, n0 = (wv >> 1) << 5;
    f32x4 acc[2][2];
    mm_block(Ah, Al, Bh, Bl, m0, n0, l15, q, acc);
    #pragma unroll
    for (int u = 0; u < 2; ++u) {
        int n = n0 + (u << 4) + l15;
        float sun = su_k[n], vn = v_k[n];
        #pragma unroll
        for (int ti = 0; ti < 2; ++ti) {
            int wb = m0 + (ti << 4) + (q << 2);
            float4 mu4 = *(const float4*)&muS[wb];
            float4 rs4 = *(const float4*)&rsS[wb];
            float4 o;
            o.x = rs4.x * (acc[ti][u][0] - mu4.x * sun) + vn;
            o.y = rs4.y * (acc[ti][u][1] - mu4.y * sun) + vn;
            o.z = rs4.z * (acc[ti][u][2] - mu4.z * sun) + vn;
            o.w = rs4.w * (acc[ti][u][3] - mu4.w * sun) + vn;
            *(float4*)&planes[((size_t)(b * 64 + n) * 64 + h) * 64 + wb] = o;
        }
    }
}

// ---------------- k_spec: spectral transform (unchanged math) ----------------
__global__ __launch_bounds__(256, 3) void k_spec(
    float* __restrict__ planes,
    const unsigned short* __restrict__ cos_hi, const unsigned short* __restrict__ cos_lo,
    const float* __restrict__ wexpT) {
    __shared__ short Ch[4096], Cl[4096];
    __shared__ short D0h[4096], D0l[4096];
    __shared__ short D1h[4096], D1l[4096];
    int b = blockIdx.x >> 6, c = blockIdx.x & 63;
    float* po = planes + (size_t)(b * 64 + c) * 4096;
    int t = threadIdx.x;
    int lane = t & 63, wv = t >> 6;
    int q = lane >> 4, l15 = lane & 15;
    int m0 = (wv & 1) << 5, n0 = (wv >> 1) << 5;

    {
        int r = t >> 2, cb = (t & 3) << 4;
        #pragma unroll
        for (int p = 0; p < 2; ++p) {
            int chunk = (cb >> 3) + p;
            int a = (r << 7) + (((chunk ^ (r & 7)) << 4));
            *(uint4*)((char*)Ch + a) = *(const uint4*)&cos_hi[r * 64 + cb + p * 8];
            *(uint4*)((char*)Cl + a) = *(const uint4*)&cos_lo[r * 64 + cb + p * 8];
        }
    }
    {
        int w = t & 63, h0 = (t >> 6) << 4;
        float v[16];
        #pragma unroll
        for (int j = 0; j < 16; ++j) v[j] = po[(h0 + j) * 64 + w];
        #pragma unroll
        for (int g = 0; g < 4; ++g) {
            int col = h0 + (g << 2);
            int a = swa(w, col);
            us4 hv, lv;
            #pragma unroll
            for (int r = 0; r < 4; ++r) {
                float f = v[(g << 2) + r];
                hv[r] = bfhi(f);
                lv[r] = bfhi(f - hif(f));
            }
            *(us4*)((char*)D0h + a) = hv;
            *(us4*)((char*)D0l + a) = lv;
        }
    }
    __syncthreads();

    f32x4 acc[2][2];

#define WB_T(Dh, Dl)                                                                \
    {                                                                               \
        _Pragma("unroll")                                                           \
        for (int ti = 0; ti < 2; ++ti)                                              \
            _Pragma("unroll")                                                       \
            for (int u = 0; u < 2; ++u) {                                           \
                int row = n0 + (u << 4) + l15;                                      \
                int col = m0 + (ti << 4) + (q << 2);                                \
                int a = swa(row, col);                                              \
                us4 hv, lv;                                                         \
                _Pragma("unroll")                                                   \
                for (int r = 0; r < 4; ++r) {                                       \
                    float f = acc[ti][u][r];                                        \
                    hv[r] = bfhi(f);                                                \
                    lv[r] = bfhi(f - hif(f));                                       \
                }                                                                   \
                *(us4*)((char*)Dh + a) = hv;                                        \
                *(us4*)((char*)Dl + a) = lv;                                        \
            }                                                                       \
    }

    // M1
    mm_block(D0h, D0l, Ch, Cl, m0, n0, l15, q, acc);
    WB_T(D1h, D1l)
    __syncthreads();
    // M2 + gate
    mm_block(D1h, D1l, Ch, Cl, m0, n0, l15, q, acc);
    {
        const float* wx = wexpT + (size_t)c * 4096;
        #pragma unroll
        for (int ti = 0; ti < 2; ++ti)
            #pragma unroll
            for (int u = 0; u < 2; ++u)
                #pragma unroll
                for (int r = 0; r < 4; ++r) {
                    int n = m0 + (ti << 4) + (q << 2) + r;
                    int m = n0 + (u << 4) + l15;
                    acc[ti][u][r] *= wx[n * 64 + m];
                }
    }
    WB_T(D0h, D0l)
    __syncthreads();
    // M3 (row-major WB via u16 scatter)
    mm_block(Ch, Cl, D0h, D0l, m0, n0, l15, q, acc);
    {
        #pragma unroll
        for (int ti = 0; ti < 2; ++ti)
            #pragma unroll
            for (int u = 0; u < 2; ++u)
                #pragma unroll
                for (int r = 0; r < 4; ++r) {
                    int row = m0 + (ti << 4) + (q << 2) + r;
                    int col = n0 + (u << 4) + l15;
                    int a = swa(row, col);
                    float f = acc[ti][u][r];
                    *(unsigned short*)((char*)D1h + a) = bfhi(f);
                    *(unsigned short*)((char*)D1l + a) = bfhi(f - hif(f));
                }
    }
    __syncthreads();
    // M4 -> global in place
    mm_block(D1h, D1l, Ch, Cl, m0, n0, l15, q, acc);
    {
        #pragma unroll
        for (int ti = 0; ti < 2; ++ti)
            #pragma unroll
            for (int u = 0; u < 2; ++u)
                #pragma unroll
                for (int r = 0; r < 4; ++r) {
                    int h = m0 + (ti << 4) + (q << 2) + r;
                    int w = n0 + (u << 4) + l15;
                    po[h * 64 + w] = acc[ti][u][r];
                }
    }
#undef WB_T
}

// ---------------- k_out: out = ((LN(t)*g_o+b_o)*siluz)@Wo + bo ----------------
__global__ __launch_bounds__(256, 3) void k_out(
    const float* __restrict__ planes, const float* __restrict__ siluzT,
    const float* __restrict__ g_o, const float* __restrict__ b_o,
    const unsigned short* __restrict__ WoTh_g, const unsigned short* __restrict__ WoTl_g,
    const float* __restrict__ bo, float* __restrict__ out) {
    __shared__ short Ah[4096], Al[4096], Bh[4096], Bl[4096];
    __shared__ __align__(16) float red1[16][68], red2[16][68];
    __shared__ float muS[64], rsS[64];
    int b = blockIdx.x >> 6, h = blockIdx.x & 63;
    int t = threadIdx.x;
    #pragma unroll
    for (int p = 0; p < 2; ++p) {
        int e = t + p * 256;
        int row = e >> 3, ch = e & 7;
        int a = (row << 7) + (((ch ^ (row & 7)) << 4));
        *(uint4*)((char*)Bh + a) = *(const uint4*)&WoTh_g[row * 64 + ch * 8];
        *(uint4*)((char*)Bl + a) = *(const uint4*)&WoTl_g[row * 64 + ch * 8];
    }
    int g = t >> 4, w0 = (t & 15) << 2, c0 = g << 2;
    const float* pb = planes + (size_t)b * 262144 + h * 64;
    float4 vr[4], szr[4];
    float4 s1 = {0,0,0,0}, s2 = {0,0,0,0};
    #pragma unroll
    for (int i = 0; i < 4; ++i) {
        int c = c0 + i;
        float4 tv = *(const float4*)&pb[c * 4096 + w0];
        szr[i] = *(const float4*)&siluzT[c * 4096 + h * 64 + w0];
        vr[i] = tv;
        s1.x += tv.x; s1.y += tv.y; s1.z += tv.z; s1.w += tv.w;
        s2.x += tv.x * tv.x; s2.y += tv.y * tv.y; s2.z += tv.z * tv.z; s2.w += tv.w * tv.w;
    }
    *(float4*)&red1[g][w0] = s1;
    *(float4*)&red2[g][w0] = s2;
    __syncthreads();
    if (t < 64) {
        float a1 = 0.f, a2 = 0.f;
        #pragma unroll
        for (int j = 0; j < 16; ++j) { a1 += red1[j][t]; a2 += red2[j][t]; }
        float mu = a1 * (1.0f / 64.0f);
        float var = a2 * (1.0f / 64.0f) - mu * mu;
        muS[t] = mu; rsS[t] = rsqrtf(var + 1e-5f);
    }
    __syncthreads();
    // gate + split + transpose-write
    {
        float4 mu4 = *(const float4*)&muS[w0];
        float4 rs4 = *(const float4*)&rsS[w0];
        #pragma unroll
        for (int i = 0; i < 4; ++i) {
            int c = c0 + i;
            float go = g_o[c], boc = b_o[c];
            vr[i].x = ((vr[i].x - mu4.x) * rs4.x * go + boc) * szr[i].x;
            vr[i].y = ((vr[i].y - mu4.y) * rs4.y * go + boc) * szr[i].y;
            vr[i].z = ((vr[i].z - mu4.z) * rs4.z * go + boc) * szr[i].z;
            vr[i].w = ((vr[i].w - mu4.w) * rs4.w * go + boc) * szr[i].w;
        }
        const float* vp = (const float*)vr;
        #pragma unroll
        for (int j = 0; j < 4; ++j) {
            us4 hv, lv;
            #pragma unroll
            for (int r = 0; r < 4; ++r) {
                float f = vp[r * 4 + j];
                hv[r] = bfhi(f);
                lv[r] = bfhi(f - hif(f));
            }
            int a = swa(w0 + j, c0);
            *(us4*)((char*)Ah + a) = hv;
            *(us4*)((char*)Al + a) = lv;
        }
    }
    __syncthreads();
    int lane = t & 63, wv = t >> 6;
    int q = lane >> 4, l15 = lane & 15;
    int m0 = (wv & 1) << 5, n0 = (wv >> 1) << 5;
    f32x4 acc[2][2];
    mm_block(Ah, Al, Bh, Bl, m0, n0, l15, q, acc);
    #pragma unroll
    for (int u = 0; u < 2; ++u) {
        int o_ = n0 + (u << 4) + l15;
        float bov = bo[o_];
        #pragma unroll
        for (int ti = 0; ti < 2; ++ti) {
            int wb = m0 + (ti << 4) + (q << 2);
            float4 o;
            o.x = acc[ti][u][0] + bov;
            o.y = acc[ti][u][1] + bov;
            o.z = acc[ti][u][2] + bov;
            o.w = acc[ti][u][3] + bov;
            *(float4*)&out[((size_t)(b * 64 + o_) * 64 + h) * 64 + wb] = o;
        }
    }
}

extern "C" void kernel_launch(void* const* d_in, const int* in_sizes, int n_in,
                              void* d_out, int out_size, void* d_ws, size_t ws_size,
                              hipStream_t stream) {
    const float* x    = (const float*)d_in[0];
    const float* freq = (const float*)d_in[1];
    const float* g_k  = (const float*)d_in[2];
    const float* b_k  = (const float*)d_in[3];
    const float* Wk   = (const float*)d_in[4];
    const float* bk   = (const float*)d_in[5];
    const float* g_z  = (const float*)d_in[6];
    const float* b_z  = (const float*)d_in[7];
    const float* Wz   = (const float*)d_in[8];
    const float* bz   = (const float*)d_in[9];
    const float* g_o  = (const float*)d_in[10];
    const float* b_o  = (const float*)d_in[11];
    const float* Wo   = (const float*)d_in[12];
    const float* bo   = (const float*)d_in[13];
    float* out = (float*)d_out;

    float* ws = (float*)d_ws;
    float* planes = ws;                                   // 16777216 f
    float* siluzT = planes + 16777216;                    // 262144 f
    float* wexpT  = siluzT + 262144;                      // 262144 f
    float* freqT  = wexpT + 262144;                       // 262144 f
    float* su_k   = freqT + 262144;                       // 64
    float* v_k    = su_k + 64;
    float* su_z   = v_k + 64;
    float* v_z    = su_z + 64;
    unsigned short* cos_hi = (unsigned short*)(v_z + 64); // 4096 u16 each
    unsigned short* cos_lo = cos_hi + 4096;
    unsigned short* WkTh = cos_lo + 4096;
    unsigned short* WkTl = WkTh + 4096;
    unsigned short* WzTh = WkTl + 4096;
    unsigned short* WzTl = WzTh + 4096;
    unsigned short* WoTh = WzTl + 4096;
    unsigned short* WoTl = WoTh + 4096;

    k_pre1<<<32, 256, 0, stream>>>(g_k, b_k, Wk, bk, g_z, b_z, Wz, bz, Wo,
                                   WkTh, WkTl, su_k, v_k, WzTh, WzTl, su_z, v_z,
                                   WoTh, WoTl, cos_hi, cos_lo);
    k_pre2<<<128, 256, 0, stream>>>(freq, WzTh, WzTl, su_z, v_z, siluzT, wexpT, freqT);
    k_k<<<4096, 256, 0, stream>>>(x, freqT, WkTh, WkTl, su_k, v_k, planes);
    k_spec<<<4096, 256, 0, stream>>>(planes, cos_hi, cos_lo, wexpT);
    k_out<<<4096, 256, 0, stream>>>(planes, siluzT, g_o, b_o, WoTh, WoTl, bo, out);
}